// Round 11
// baseline (109.903 us; speedup 1.0000x reference)
//
#include <hip/hip_runtime.h>
#include <math.h>

// LowRankChristoffel via MFMA, R11:
//   R10 (105us) was latency-bound on 8 stride-16 scalar L2 loads of U per
//   step (VALU 14%, Mfma 1.2%). Fix: stage U^T ONCE per WG as bf16 in LDS
//   with derived conflict-free padding; B-frag becomes one ds_read_b128.
//   512-thr WG, 16 rows, K-split 8x256, grid 1024. Phase C as R10 + padding.
//
// Fragment layouts (gfx950 v_mfma_f32_16x16x32_bf16, m89-verified):
//   A[m][k]: m = lane&15, k = (lane>>4)*8 + e
//   B[k][n]: n = lane&15, k = (lane>>4)*8 + e
//   C/D:     col n = lane&15, row m = (lane>>4)*4 + i

typedef short bf16x8 __attribute__((ext_vector_type(8)));
typedef float f32x4  __attribute__((ext_vector_type(4)));

constexpr int D_DIM   = 2048;
constexpr int R_DIM   = 16;
constexpr int MROWS   = 16;    // rows per WG
constexpr int THREADS = 512;   // 8 waves
constexpr int WAVES   = 8;
constexpr int KSLICE  = 256;   // K per wave in phase A
constexpr int KSTEPS  = KSLICE / 32;   // 8
// u_lds row pad: row stride 2072 bf16 -> word-stride 1036 -> lane bank-quad
// (3*l16+lk)%8 -> exactly 8 word-accesses per bank = b128 floor (no extras).
constexpr int DP      = 2072;

__device__ __forceinline__ unsigned f2bf(float f) {   // exact RTNE fp32->bf16
    unsigned u = __float_as_uint(f);
    return (u + 0x7fffu + ((u >> 16) & 1u)) >> 16;
}
__device__ __forceinline__ float bf2f(unsigned b) { return __uint_as_float(b << 16); }
__device__ __forceinline__ float clamp5(float v) { return fminf(fmaxf(v, -5.0f), 5.0f); }
__device__ __forceinline__ float dot4f(float4 a, float4 b) {
    return a.x * b.x + a.y * b.y + a.z * b.z + a.w * b.w;
}

extern "C" __global__ void __launch_bounds__(THREADS)
lrc_mfma(const float* __restrict__ v, const float* __restrict__ x,
         const float* __restrict__ U, const float* __restrict__ W,
         const float* __restrict__ Vw, float* __restrict__ out, int nrows)
{
    __shared__ unsigned short u_lds[R_DIM * DP];          // 66.3 KB, U^T bf16
    __shared__ float proj_lds[WAVES][MROWS][17];          // padded
    __shared__ float xv_lds[WAVES][MROWS];
    __shared__ float sq_lds[MROWS][17];                   // padded
    __shared__ float fac_lds[MROWS];

    const int tid  = threadIdx.x;
    const int lane = tid & 63;
    const int wave = tid >> 6;       // 0..7
    const int l16  = lane & 15;
    const int lk   = lane >> 4;      // 0..3
    const int row0 = blockIdx.x * MROWS;

    // ---- stage U^T bf16: thread owns U d-rows 4t..4t+3, packs pairs ----
    {
        const float* up = U + (size_t)tid * 4 * R_DIM;
        float c0[R_DIM], c1[R_DIM], c2[R_DIM], c3[R_DIM];
        #pragma unroll
        for (int q = 0; q < 4; ++q) {
            *reinterpret_cast<float4*>(&c0[q * 4]) = reinterpret_cast<const float4*>(up)[q];
            *reinterpret_cast<float4*>(&c1[q * 4]) = reinterpret_cast<const float4*>(up + 16)[q];
            *reinterpret_cast<float4*>(&c2[q * 4]) = reinterpret_cast<const float4*>(up + 32)[q];
            *reinterpret_cast<float4*>(&c3[q * 4]) = reinterpret_cast<const float4*>(up + 48)[q];
        }
        #pragma unroll
        for (int r = 0; r < R_DIM; ++r) {
            uint2 pk;
            pk.x = f2bf(c0[r]) | (f2bf(c1[r]) << 16);
            pk.y = f2bf(c2[r]) | (f2bf(c3[r]) << 16);
            *reinterpret_cast<uint2*>(&u_lds[r * DP + tid * 4]) = pk;  // byte r*4144+8t
        }
    }
    __syncthreads();

    // ---- phase A: proj tile MFMA (wave K-slice 256) + fp32 x.Vw ----
    {
        int grow = row0 + l16;
        if (grow >= nrows) grow = nrows - 1;
        const float* vp = v + (size_t)grow * D_DIM;
        const float* xp = x + (size_t)grow * D_DIM;

        f32x4 acc = {0.f, 0.f, 0.f, 0.f};
        float xv = 0.f;
        const int kb = wave * KSLICE + lk * 8;

        #pragma unroll
        for (int s = 0; s < KSTEPS; ++s) {
            const int k = kb + s * 32;
            const float4 va = *reinterpret_cast<const float4*>(vp + k);
            const float4 vb = *reinterpret_cast<const float4*>(vp + k + 4);
            const float4 xa = *reinterpret_cast<const float4*>(xp + k);
            const float4 xb = *reinterpret_cast<const float4*>(xp + k + 4);
            const float4 wa = *reinterpret_cast<const float4*>(Vw + k);
            const float4 wb = *reinterpret_cast<const float4*>(Vw + k + 4);

            // B-frag: one aligned b128 LDS read (conflict-free by DP pad)
            const bf16x8 bu = *reinterpret_cast<const bf16x8*>(&u_lds[l16 * DP + k]);

            // A-frag hi/lo split of v
            const float vf[8] = {va.x, va.y, va.z, va.w, vb.x, vb.y, vb.z, vb.w};
            bf16x8 ah, al;
            #pragma unroll
            for (int e = 0; e < 8; ++e) {
                const unsigned h = f2bf(vf[e]);
                ah[e] = (short)h;
                al[e] = (short)f2bf(vf[e] - bf2f(h));
            }
            acc = __builtin_amdgcn_mfma_f32_16x16x32_bf16(ah, bu, acc, 0, 0, 0);
            acc = __builtin_amdgcn_mfma_f32_16x16x32_bf16(al, bu, acc, 0, 0, 0);

            xv += dot4f(xa, wa) + dot4f(xb, wb);
        }
        xv += __shfl_xor(xv, 16, 64);
        xv += __shfl_xor(xv, 32, 64);

        #pragma unroll
        for (int i = 0; i < 4; ++i) proj_lds[wave][lk * 4 + i][l16] = acc[i];
        if (lk == 0) xv_lds[wave][l16] = xv;
    }
    __syncthreads();

    // ---- cross-wave K-reduce + square + sigmoid ----
    if (tid < MROWS * R_DIM) {
        const int m = tid >> 4, r = tid & 15;
        float p = 0.f;
        #pragma unroll
        for (int w = 0; w < WAVES; ++w) p += proj_lds[w][m][r];
        sq_lds[m][r] = p * p;
    }
    if (tid < MROWS) {
        float s = 0.f;
        #pragma unroll
        for (int w = 0; w < WAVES; ++w) s += xv_lds[w][tid];
        fac_lds[tid] = 1.0f + 1.0f / (1.0f + __expf(-s));
    }
    __syncthreads();

    // ---- phase C: out = sq @ W^T; wave owns d-slice [wave*256, +256) ----
    {
        bf16x8 asq;
        #pragma unroll
        for (int e = 0; e < 8; ++e) {
            const int kk = lk * 8 + e;
            asq[e] = (kk < R_DIM) ? (short)f2bf(sq_lds[l16][kk]) : (short)0;
        }
        float fr[4];
        #pragma unroll
        for (int i = 0; i < 4; ++i) fr[i] = fac_lds[lk * 4 + i];

        const int dbase = wave * 256;
        #pragma unroll 4
        for (int c = 0; c < 16; ++c) {
            const int d0 = dbase + c * 16;
            bf16x8 bw;
            if (lk < 2) {   // k = lk*8+e in 0..15 -> W[d0+l16][k]
                const float* wp = W + (size_t)(d0 + l16) * R_DIM + lk * 8;
                const float4 q0 = *reinterpret_cast<const float4*>(wp);
                const float4 q1 = *reinterpret_cast<const float4*>(wp + 4);
                bw[0] = (short)f2bf(q0.x); bw[1] = (short)f2bf(q0.y);
                bw[2] = (short)f2bf(q0.z); bw[3] = (short)f2bf(q0.w);
                bw[4] = (short)f2bf(q1.x); bw[5] = (short)f2bf(q1.y);
                bw[6] = (short)f2bf(q1.z); bw[7] = (short)f2bf(q1.w);
            } else {
                #pragma unroll
                for (int e = 0; e < 8; ++e) bw[e] = 0;
            }
            f32x4 o = {0.f, 0.f, 0.f, 0.f};
            o = __builtin_amdgcn_mfma_f32_16x16x32_bf16(asq, bw, o, 0, 0, 0);
            #pragma unroll
            for (int i = 0; i < 4; ++i) {
                const int rr = row0 + lk * 4 + i;
                if (rr < nrows)
                    out[(size_t)rr * D_DIM + d0 + l16] = clamp5(o[i] * fr[i]);
            }
        }
    }
}

extern "C" void kernel_launch(void* const* d_in, const int* in_sizes, int n_in,
                              void* d_out, int out_size, void* d_ws, size_t ws_size,
                              hipStream_t stream) {
    const float* v  = (const float*)d_in[0];
    const float* x  = (const float*)d_in[1];
    const float* U  = (const float*)d_in[2];
    const float* W  = (const float*)d_in[3];
    const float* Vw = (const float*)d_in[4];
    float* out = (float*)d_out;

    const int nrows = in_sizes[0] / D_DIM;          // B*S = 16384
    const int grid  = (nrows + MROWS - 1) / MROWS;  // 1024 WGs

    lrc_mfma<<<grid, THREADS, 0, stream>>>(v, x, U, W, Vw, out, nrows);
}

// Round 12
// 91.937 us; speedup vs baseline: 1.1954x; 1.1954x over previous
//
#include <hip/hip_runtime.h>
#include <math.h>

// LowRankChristoffel R12: out = clip((((v@U)^2)@W^T)*(1+sigmoid(x@Vw)), +-5)
// B=4,S=4096,D=2048,R=16 fp32. Diagnosis R4-R11: every variant latency-bound
// at ~2TB/s with <=16 waves/CU (grid/LDS caps). Fix: 32 waves/CU.
//  - prologue packs U^T and W^T as bf16 PAIRS (uint32) into d_ws (64KB each).
//  - main: copy U-pack to LDS (64KB -> 2 WGs/CU at 1024thr = 32 waves/CU).
//  - phase 1: per r-pair one uint4 LDS read (8 words/bank exactly -> b128
//    floor, 0 conflicts), unpack shift/mask, fp32 FMA (v unquantized).
//  - butterfly; square+sigmoid in-register (R8 style, no 2nd barrier);
//    phase 2 streams W-pack from L1/L2 (64KB hot), nt stores. Waves desync.

typedef float f32x4 __attribute__((ext_vector_type(4)));

constexpr int D_DIM   = 2048;
constexpr int R_DIM   = 16;
constexpr int RPAIR   = 8;        // 16 r = 8 packed pairs
constexpr int ROWS    = 32;       // rows per WG
constexpr int THREADS = 1024;     // 16 waves
constexpr int RB      = 2;        // rows per wave
constexpr int PACKN   = RPAIR * D_DIM;   // 16384 words per matrix

__device__ __forceinline__ unsigned f2bf(float f) {   // exact RTNE fp32->bf16
    unsigned u = __float_as_uint(f);
    return (u + 0x7fffu + ((u >> 16) & 1u)) >> 16;
}
__device__ __forceinline__ float lo2f(unsigned w) { return __uint_as_float(w << 16); }
__device__ __forceinline__ float hi2f(unsigned w) { return __uint_as_float(w & 0xffff0000u); }
__device__ __forceinline__ float clamp5(float v) { return fminf(fmaxf(v, -5.0f), 5.0f); }
__device__ __forceinline__ float dot4(float4 a, float4 b) {
    return a.x * b.x + a.y * b.y + a.z * b.z + a.w * b.w;
}

// ---- prologue: pack U^T, W^T as bf16 pairs into ws[0:16384], ws[16384:32768]
extern "C" __global__ void pack_uw(const float* __restrict__ U,
                                   const float* __restrict__ W,
                                   unsigned* __restrict__ ws) {
    const int i = blockIdx.x * 256 + threadIdx.x;     // 0..16383
    if (i < PACKN) {
        const int p = i >> 11;            // r-pair 0..7
        const int d = i & (D_DIM - 1);    // 0..2047
        ws[i]         = f2bf(U[d * R_DIM + 2 * p]) | (f2bf(U[d * R_DIM + 2 * p + 1]) << 16);
        ws[PACKN + i] = f2bf(W[d * R_DIM + 2 * p]) | (f2bf(W[d * R_DIM + 2 * p + 1]) << 16);
    }
}

extern "C" __global__ void __launch_bounds__(THREADS)
lrc_kernel(const float* __restrict__ v, const float* __restrict__ x,
           const unsigned* __restrict__ uw, const float* __restrict__ Vw,
           float* __restrict__ out, int nrows)
{
    __shared__ unsigned u_lds[PACKN];    // 64 KB: bf16-pair U^T [8][2048]

    const int tid  = threadIdx.x;
    const int lane = tid & 63;
    const int wave = tid >> 6;          // 0..15
    const int row0 = blockIdx.x * ROWS;

    // ---- stage U-pack into LDS: pure uint4 copy, coalesced, no conversion ----
    {
        const uint4* src = reinterpret_cast<const uint4*>(uw);
        uint4* dst = reinterpret_cast<uint4*>(u_lds);
        #pragma unroll
        for (int i = 0; i < PACKN / 4 / THREADS; ++i)   // 4 iters
            dst[i * THREADS + tid] = src[i * THREADS + tid];
    }
    __syncthreads();                     // the ONLY barrier

    // ---- phase 1: wave owns rows rl0, rl0+1 ----
    const int rl0 = wave * RB;
    const bool rows_ok = (row0 + rl0 + RB) <= nrows;
    const float* vb = v + (size_t)(row0 + rl0) * D_DIM;
    const float* xb = x + (size_t)(row0 + rl0) * D_DIM;

    float pp[RB][R_DIM];
    float xv[RB];
    #pragma unroll
    for (int k = 0; k < RB; ++k) {
        xv[k] = 0.0f;
        #pragma unroll
        for (int r = 0; r < R_DIM; ++r) pp[k][r] = 0.0f;
    }

    if (rows_ok) {
        for (int i = 0; i < D_DIM / 256; ++i) {      // 8 iters
            const int d0 = i * 256 + lane * 4;
            float4 v4[RB], x4[RB];
            #pragma unroll
            for (int k = 0; k < RB; ++k) {
                v4[k] = *reinterpret_cast<const float4*>(vb + (size_t)k * D_DIM + d0);
                x4[k] = *reinterpret_cast<const float4*>(xb + (size_t)k * D_DIM + d0);
            }
            const float4 vw4 = *reinterpret_cast<const float4*>(Vw + d0);   // L1-hot 8KB
            #pragma unroll
            for (int k = 0; k < RB; ++k) xv[k] += dot4(x4[k], vw4);

            #pragma unroll
            for (int p = 0; p < RPAIR; ++p) {
                const uint4 uu = *reinterpret_cast<const uint4*>(&u_lds[p * D_DIM + d0]);
                const float l0 = lo2f(uu.x), h0 = hi2f(uu.x);
                const float l1 = lo2f(uu.y), h1 = hi2f(uu.y);
                const float l2 = lo2f(uu.z), h2 = hi2f(uu.z);
                const float l3 = lo2f(uu.w), h3 = hi2f(uu.w);
                #pragma unroll
                for (int k = 0; k < RB; ++k) {
                    pp[k][2 * p]     += v4[k].x * l0 + v4[k].y * l1 + v4[k].z * l2 + v4[k].w * l3;
                    pp[k][2 * p + 1] += v4[k].x * h0 + v4[k].y * h1 + v4[k].z * h2 + v4[k].w * h3;
                }
            }
        }
    }

    // ---- butterfly: all lanes end with full sums ----
    #pragma unroll
    for (int s = 32; s >= 1; s >>= 1) {
        #pragma unroll
        for (int k = 0; k < RB; ++k) {
            xv[k] += __shfl_xor(xv[k], s, 64);
            #pragma unroll
            for (int r = 0; r < R_DIM; ++r) pp[k][r] += __shfl_xor(pp[k][r], s, 64);
        }
    }

    // square + modulation in registers
    float fac[RB];
    #pragma unroll
    for (int k = 0; k < RB; ++k) {
        fac[k] = 1.0f + 1.0f / (1.0f + __expf(-xv[k]));
        #pragma unroll
        for (int r = 0; r < R_DIM; ++r) pp[k][r] = pp[k][r] * pp[k][r];
    }

    // ---- phase 2 (no barrier): wave streams its own 2 rows; W-pack from L1/L2 ----
    if (rows_ok) {
        const unsigned* wt = uw + PACKN;
        float* ob = out + (size_t)(row0 + rl0) * D_DIM;
        for (int i = 0; i < D_DIM / 256; ++i) {
            const int d0 = i * 256 + lane * 4;
            f32x4 o0 = {0.f, 0.f, 0.f, 0.f}, o1 = {0.f, 0.f, 0.f, 0.f};
            #pragma unroll
            for (int p = 0; p < RPAIR; ++p) {
                const uint4 ww = *reinterpret_cast<const uint4*>(&wt[p * D_DIM + d0]);
                const float l0 = lo2f(ww.x), h0 = hi2f(ww.x);
                const float l1 = lo2f(ww.y), h1 = hi2f(ww.y);
                const float l2 = lo2f(ww.z), h2 = hi2f(ww.z);
                const float l3 = lo2f(ww.w), h3 = hi2f(ww.w);
                const float sa = pp[0][2 * p], sb = pp[0][2 * p + 1];
                const float sc = pp[1][2 * p], sd = pp[1][2 * p + 1];
                o0.x += sa * l0 + sb * h0;  o0.y += sa * l1 + sb * h1;
                o0.z += sa * l2 + sb * h2;  o0.w += sa * l3 + sb * h3;
                o1.x += sc * l0 + sd * h0;  o1.y += sc * l1 + sd * h1;
                o1.z += sc * l2 + sd * h2;  o1.w += sc * l3 + sd * h3;
            }
            o0.x = clamp5(o0.x * fac[0]); o0.y = clamp5(o0.y * fac[0]);
            o0.z = clamp5(o0.z * fac[0]); o0.w = clamp5(o0.w * fac[0]);
            o1.x = clamp5(o1.x * fac[1]); o1.y = clamp5(o1.y * fac[1]);
            o1.z = clamp5(o1.z * fac[1]); o1.w = clamp5(o1.w * fac[1]);
            __builtin_nontemporal_store(o0, reinterpret_cast<f32x4*>(ob + d0));
            __builtin_nontemporal_store(o1, reinterpret_cast<f32x4*>(ob + D_DIM + d0));
        }
    }
}

extern "C" void kernel_launch(void* const* d_in, const int* in_sizes, int n_in,
                              void* d_out, int out_size, void* d_ws, size_t ws_size,
                              hipStream_t stream) {
    const float* v  = (const float*)d_in[0];
    const float* x  = (const float*)d_in[1];
    const float* U  = (const float*)d_in[2];
    const float* W  = (const float*)d_in[3];
    const float* Vw = (const float*)d_in[4];
    float* out = (float*)d_out;
    unsigned* uw = (unsigned*)d_ws;               // 128 KiB scratch

    const int nrows = in_sizes[0] / D_DIM;        // B*S = 16384
    const int grid  = (nrows + ROWS - 1) / ROWS;  // 512 WGs -> 2/CU

    pack_uw<<<(PACKN + 255) / 256, 256, 0, stream>>>(U, W, uw);
    lrc_kernel<<<grid, THREADS, 0, stream>>>(v, x, uw, Vw, out, nrows);
}